// Round 1
// baseline (281.997 us; speedup 1.0000x reference)
//
#include <hip/hip_runtime.h>
#include <hip/hip_bf16.h>
#include <math.h>

#define N_CELLS 65536
#define D_DIM   128
#define K_PROTO 2048
#define BM 128
#define BN 128

typedef __attribute__((ext_vector_type(8))) short bf16x8;
typedef __attribute__((ext_vector_type(4))) float f32x4;

// ---- order-preserving float<->uint mapping for atomic min/max ----
__device__ __forceinline__ unsigned int map_f2u(float f) {
  unsigned int u = __float_as_uint(f);
  return (u & 0x80000000u) ? ~u : (u | 0x80000000u);
}
__device__ __forceinline__ float unmap_u2f(unsigned int u) {
  unsigned int b = (u & 0x80000000u) ? (u ^ 0x80000000u) : ~u;
  return __uint_as_float(b);
}

// RTN-even float -> bf16 (bit pattern), matches __float2bfloat16 for normals
__device__ __forceinline__ unsigned int f2bf(float f) {
  unsigned int u = __float_as_uint(f);
  return ((u + 0x7FFFu + ((u >> 16) & 1u)) >> 16) & 0xFFFFu;
}

__device__ __forceinline__ void async16(const void* g, void* l) {
  __builtin_amdgcn_global_load_lds(
      (const __attribute__((address_space(1))) unsigned int*)g,
      (__attribute__((address_space(3))) unsigned int*)l,
      16, 0, 0);
}

// ---- K1: row-normalize x -> z (f32 out) + zb (packed bf16 pairs in ws) ----
__global__ __launch_bounds__(256) void normalize_k(
    const float* __restrict__ x, float* __restrict__ z,
    unsigned int* __restrict__ zb) {
  int wid  = threadIdx.x >> 6;
  int lane = threadIdx.x & 63;
  int row  = blockIdx.x * 4 + wid;
  const float2* xr = (const float2*)(x + (size_t)row * D_DIM);
  float2 v = xr[lane];
  float s = v.x * v.x + v.y * v.y;
  #pragma unroll
  for (int off = 1; off < 64; off <<= 1) s += __shfl_xor(s, off, 64);
  float inv = 1.0f / fmaxf(sqrtf(s), 1e-12f);
  float zx = v.x * inv, zy = v.y * inv;
  float2* zr = (float2*)(z + (size_t)row * D_DIM);
  zr[lane] = make_float2(zx, zy);
  zb[(size_t)row * (D_DIM / 2) + lane] = (f2bf(zy) << 16) | f2bf(zx);
}

// ---- K2: W -> bf16 (packed) + ww row norms; block 0 also writes cvae ----
__global__ __launch_bounds__(256) void wprep_k(
    const float* __restrict__ W, unsigned int* __restrict__ wb,
    float* __restrict__ ww,
    const float* __restrict__ recon, const float* __restrict__ kl,
    const float* __restrict__ mmd, float* __restrict__ scal) {
  if (blockIdx.x == 0 && threadIdx.x == 0) {
    scal[0] = recon[0] + 0.5f * kl[0] + mmd[0];  // cvae_loss
  }
  int wid  = threadIdx.x >> 6;
  int lane = threadIdx.x & 63;
  int row  = blockIdx.x * 4 + wid;
  const float2* wr = (const float2*)(W + (size_t)row * D_DIM);
  float2 v = wr[lane];
  float s = v.x * v.x + v.y * v.y;
  #pragma unroll
  for (int off = 1; off < 64; off <<= 1) s += __shfl_xor(s, off, 64);
  if (lane == 0) ww[row] = s;
  wb[(size_t)row * (D_DIM / 2) + lane] = (f2bf(v.y) << 16) | f2bf(v.x);
}

// ---- K3: logits = zb @ wb^T (bf16 MFMA, f32 acc) + fused min/max epilogue ----
__global__ __launch_bounds__(256, 2) void gemm_k(
    const unsigned short* __restrict__ zb, const unsigned short* __restrict__ wb,
    const float* __restrict__ ww, float* __restrict__ logits,
    unsigned int* __restrict__ rowmin_u, unsigned int* __restrict__ colmax_u) {
  __shared__ unsigned short Als[BM * D_DIM];  // 32 KB, XOR-swizzled storage
  __shared__ unsigned short Bls[BN * D_DIM];  // 32 KB

  // XCD-chunked bijective swizzle: 8192 blocks = 8 XCDs x 1024
  int bid = blockIdx.x;
  int swz = (bid & 7) * 1024 + (bid >> 3);
  int nt  = swz & 15;   // 16 col tiles (protos)
  int mt  = swz >> 4;   // 512 row tiles (cells)

  int tid  = threadIdx.x;
  int lane = tid & 63;
  int wid  = tid >> 6;

  // stage A,B: 8 iters x 256 thr x 16B each; linear LDS dest, pre-swizzled src
  #pragma unroll
  for (int it = 0; it < 8; ++it) {
    int o  = (it * 256 + tid) * 16;   // linear dest byte offset
    int r  = o >> 8;                  // row (256 B per row)
    int pb = o & 255;                 // physical byte col
    int lb = pb ^ ((r & 7) << 4);     // logical byte col (involution)
    const char* gA = (const char*)zb + ((size_t)(mt * BM + r) * (D_DIM * 2) + lb);
    const char* gB = (const char*)wb + ((size_t)(nt * BN + r) * (D_DIM * 2) + lb);
    char* lA = (char*)Als + (it * 4096 + wid * 1024);  // wave-uniform base
    char* lB = (char*)Bls + (it * 4096 + wid * 1024);
    async16(gA, lA);
    async16(gB, lB);
  }
  __syncthreads();

  int wrow = (wid >> 1) * 64;
  int wcol = (wid & 1) * 64;
  int l15  = lane & 15;
  int hi   = lane >> 4;
  int hb   = hi * 16;  // byte offset of this lane's k-group

  f32x4 acc[4][4];
  #pragma unroll
  for (int i = 0; i < 4; ++i)
    #pragma unroll
    for (int j = 0; j < 4; ++j)
      acc[i][j] = f32x4{0.f, 0.f, 0.f, 0.f};

  #pragma unroll
  for (int kk = 0; kk < 4; ++kk) {
    int cb = kk * 64 + hb;  // logical col byte
    bf16x8 a[4], b[4];
    #pragma unroll
    for (int i = 0; i < 4; ++i) {
      int r = wrow + i * 16 + l15;
      a[i] = *(const bf16x8*)((const char*)Als + r * 256 + (cb ^ ((r & 7) << 4)));
    }
    #pragma unroll
    for (int j = 0; j < 4; ++j) {
      int r = wcol + j * 16 + l15;
      b[j] = *(const bf16x8*)((const char*)Bls + r * 256 + (cb ^ ((r & 7) << 4)));
    }
    #pragma unroll
    for (int i = 0; i < 4; ++i)
      #pragma unroll
      for (int j = 0; j < 4; ++j)
        acc[i][j] = __builtin_amdgcn_mfma_f32_16x16x32_bf16(a[i], b[j], acc[i][j], 0, 0, 0);
  }

  // epilogue: store logits f32, track rowmin(ww-2L) and colmax(L)
  size_t growbase = (size_t)mt * BM + wrow;
  int    gcolbase = nt * BN + wcol;

  float wwj[4];
  #pragma unroll
  for (int j = 0; j < 4; ++j) wwj[j] = ww[gcolbase + j * 16 + l15];

  #pragma unroll
  for (int i = 0; i < 4; ++i) {
    #pragma unroll
    for (int r = 0; r < 4; ++r) {
      size_t grow = growbase + (size_t)(i * 16 + hi * 4 + r);
      float* lp = logits + grow * K_PROTO + gcolbase + l15;
      float vmin = 1e30f;
      #pragma unroll
      for (int j = 0; j < 4; ++j) {
        float lv = acc[i][j][r];
        lp[j * 16] = lv;
        vmin = fminf(vmin, wwj[j] - 2.0f * lv);
      }
      #pragma unroll
      for (int s2 = 1; s2 < 16; s2 <<= 1) vmin = fminf(vmin, __shfl_xor(vmin, s2, 64));
      if (l15 == 0) atomicMin(&rowmin_u[grow], map_f2u(vmin));
    }
  }

  #pragma unroll
  for (int j = 0; j < 4; ++j) {
    float vmax = -1e30f;
    #pragma unroll
    for (int i = 0; i < 4; ++i)
      #pragma unroll
      for (int r = 0; r < 4; ++r) vmax = fmaxf(vmax, acc[i][j][r]);
    vmax = fmaxf(vmax, __shfl_xor(vmax, 16, 64));
    vmax = fmaxf(vmax, __shfl_xor(vmax, 32, 64));
    if (hi == 0) atomicMax(&colmax_u[gcolbase + j * 16 + l15], map_f2u(vmax));
  }
}

// ---- K4: propagation = mean_n sqrt(max(1 + rowmin, 0)) ----
__global__ __launch_bounds__(1024) void prop_k(
    const unsigned int* __restrict__ rowmin_u, float* __restrict__ out) {
  __shared__ float sbuf[16];
  float s = 0.f;
  for (int idx = threadIdx.x; idx < N_CELLS; idx += 1024)
    s += sqrtf(fmaxf(1.0f + unmap_u2f(rowmin_u[idx]), 0.0f));
  #pragma unroll
  for (int off = 1; off < 64; off <<= 1) s += __shfl_xor(s, off, 64);
  int wid = threadIdx.x >> 6, lane = threadIdx.x & 63;
  if (lane == 0) sbuf[wid] = s;
  __syncthreads();
  if (threadIdx.x == 0) {
    float t = 0.f;
    #pragma unroll
    for (int w = 0; w < 16; ++w) t += sbuf[w];
    out[0] = t * (1.0f / N_CELLS);
  }
}

// ---- K5: emb_similarity = mean_k sqrt(max(1 + ww[k] - 2*colmax[k], 0)) ----
__global__ __launch_bounds__(1024) void emb_k(
    const unsigned int* __restrict__ colmax_u, const float* __restrict__ ww,
    float* __restrict__ out) {
  __shared__ float sbuf[16];
  float s = 0.f;
  for (int idx = threadIdx.x; idx < K_PROTO; idx += 1024)
    s += sqrtf(fmaxf(1.0f + ww[idx] - 2.0f * unmap_u2f(colmax_u[idx]), 0.0f));
  #pragma unroll
  for (int off = 1; off < 64; off <<= 1) s += __shfl_xor(s, off, 64);
  int wid = threadIdx.x >> 6, lane = threadIdx.x & 63;
  if (lane == 0) sbuf[wid] = s;
  __syncthreads();
  if (threadIdx.x == 0) {
    float t = 0.f;
    #pragma unroll
    for (int w = 0; w < 16; ++w) t += sbuf[w];
    out[0] = t * (1.0f / K_PROTO);
  }
}

extern "C" void kernel_launch(void* const* d_in, const int* in_sizes, int n_in,
                              void* d_out, int out_size, void* d_ws, size_t ws_size,
                              hipStream_t stream) {
  const float* x     = (const float*)d_in[0];
  const float* W     = (const float*)d_in[1];
  const float* recon = (const float*)d_in[2];
  const float* kl    = (const float*)d_in[3];
  const float* mmd   = (const float*)d_in[4];

  float* out    = (float*)d_out;
  float* z      = out;
  float* logits = out + (size_t)N_CELLS * D_DIM;
  float* scal   = logits + (size_t)N_CELLS * K_PROTO;  // [cvae, prop, emb]

  char* ws = (char*)d_ws;
  unsigned int* zb = (unsigned int*)ws;                     // 16 MiB packed bf16
  size_t off = (size_t)N_CELLS * D_DIM * 2;
  unsigned int* wb = (unsigned int*)(ws + off);             // 0.5 MiB
  off += (size_t)K_PROTO * D_DIM * 2;
  float* ww = (float*)(ws + off);                           // 8 KiB
  off += (size_t)K_PROTO * 4;
  unsigned int* rowmin_u = (unsigned int*)(ws + off);       // 256 KiB
  off += (size_t)N_CELLS * 4;
  unsigned int* colmax_u = (unsigned int*)(ws + off);       // 8 KiB

  // identities for min (0xFFFFFFFF) and max (0x00000000) in mapped-uint order
  hipMemsetAsync(rowmin_u, 0xFF, (size_t)N_CELLS * 4, stream);
  hipMemsetAsync(colmax_u, 0x00, (size_t)K_PROTO * 4, stream);

  normalize_k<<<N_CELLS / 4, 256, 0, stream>>>(x, z, zb);
  wprep_k<<<K_PROTO / 4, 256, 0, stream>>>(W, wb, ww, recon, kl, mmd, scal);
  gemm_k<<<(N_CELLS / BM) * (K_PROTO / BN), 256, 0, stream>>>(
      (const unsigned short*)zb, (const unsigned short*)wb, ww, logits,
      rowmin_u, colmax_u);
  prop_k<<<1, 1024, 0, stream>>>(rowmin_u, scal + 1);
  emb_k<<<1, 1024, 0, stream>>>(colmax_u, ww, scal + 2);
}

// Round 3
// 280.439 us; speedup vs baseline: 1.0056x; 1.0056x over previous
//
#include <hip/hip_runtime.h>
#include <hip/hip_bf16.h>
#include <math.h>

#define N_CELLS 65536
#define D_DIM   128
#define K_PROTO 2048

typedef __attribute__((ext_vector_type(8))) short bf16x8;
typedef __attribute__((ext_vector_type(4))) float f32x4;
typedef __attribute__((ext_vector_type(2))) float f32x2;

// ---- order-preserving float<->uint mapping for atomic min/max ----
__device__ __forceinline__ unsigned int map_f2u(float f) {
  unsigned int u = __float_as_uint(f);
  return (u & 0x80000000u) ? ~u : (u | 0x80000000u);
}
__device__ __forceinline__ float unmap_u2f(unsigned int u) {
  unsigned int b = (u & 0x80000000u) ? (u ^ 0x80000000u) : ~u;
  return __uint_as_float(b);
}

// RTN-even float -> bf16 bit pattern
__device__ __forceinline__ unsigned int f2bf(float f) {
  unsigned int u = __float_as_uint(f);
  return ((u + 0x7FFFu + ((u >> 16) & 1u)) >> 16) & 0xFFFFu;
}

// ---- K1: row-normalize x -> z (NT f32 out) + zb (packed bf16) + rowmin init ----
__global__ __launch_bounds__(256) void normalize_k(
    const float* __restrict__ x, float* __restrict__ z,
    unsigned int* __restrict__ zb, unsigned int* __restrict__ rowmin_u) {
  int wid  = threadIdx.x >> 6;
  int lane = threadIdx.x & 63;
  int row  = blockIdx.x * 4 + wid;
  const f32x2* xr = (const f32x2*)(x + (size_t)row * D_DIM);
  f32x2 v = xr[lane];
  float s = v.x * v.x + v.y * v.y;
  #pragma unroll
  for (int off = 1; off < 64; off <<= 1) s += __shfl_xor(s, off, 64);
  float inv = 1.0f / fmaxf(sqrtf(s), 1e-12f);
  f32x2 zv = {v.x * inv, v.y * inv};
  f32x2* zr = (f32x2*)(z + (size_t)row * D_DIM);
  __builtin_nontemporal_store(zv, zr + lane);
  zb[(size_t)row * (D_DIM / 2) + lane] = (f2bf(zv.y) << 16) | f2bf(zv.x);
  if (lane == 0) rowmin_u[row] = 0xFFFFFFFFu;  // min identity (mapped order)
}

// ---- K2: W -> bf16 + ww norms + colmax init; block 0 writes cvae ----
__global__ __launch_bounds__(256) void wprep_k(
    const float* __restrict__ W, unsigned int* __restrict__ wb,
    float* __restrict__ ww, unsigned int* __restrict__ colmax_u,
    const float* __restrict__ recon, const float* __restrict__ kl,
    const float* __restrict__ mmd, float* __restrict__ scal) {
  if (blockIdx.x == 0 && threadIdx.x == 0) {
    scal[0] = recon[0] + 0.5f * kl[0] + mmd[0];  // cvae_loss
  }
  int wid  = threadIdx.x >> 6;
  int lane = threadIdx.x & 63;
  int row  = blockIdx.x * 4 + wid;
  const f32x2* wr = (const f32x2*)(W + (size_t)row * D_DIM);
  f32x2 v = wr[lane];
  float s = v.x * v.x + v.y * v.y;
  #pragma unroll
  for (int off = 1; off < 64; off <<= 1) s += __shfl_xor(s, off, 64);
  if (lane == 0) {
    ww[row] = s;
    colmax_u[row] = 0u;  // max identity (mapped order)
  }
  wb[(size_t)row * (D_DIM / 2) + lane] = (f2bf(v.y) << 16) | f2bf(v.x);
}

// ---- K3: LDS-free GEMM: direct global->VGPR fragments, no barriers ----
__global__ __launch_bounds__(256) void gemm_k(
    const unsigned short* __restrict__ zb, const unsigned short* __restrict__ wb,
    const float* __restrict__ ww, float* __restrict__ logits,
    unsigned int* __restrict__ rowmin_u, unsigned int* __restrict__ colmax_u) {
  // XCD-chunked bijective swizzle: 8192 blocks = 8 XCDs x 1024
  int bid = blockIdx.x;
  int swz = (bid & 7) * 1024 + (bid >> 3);
  int nt  = swz & 15;   // 16 col tiles (protos)
  int mt  = swz >> 4;   // 512 row tiles (cells)

  int tid  = threadIdx.x;
  int lane = tid & 63;
  int wid  = tid >> 6;
  int wrow = (wid >> 1) * 64;
  int wcol = (wid & 1) * 64;
  int l15  = lane & 15;
  int hi   = lane >> 4;

  // fragment base addresses: row-major bf16, 256 B per row
  const char* Abase = (const char*)zb + ((size_t)(mt * 128 + wrow + l15) * 256 + hi * 16);
  const char* Bbase = (const char*)wb + ((size_t)(nt * 128 + wcol + l15) * 256 + hi * 16);

  f32x4 acc[4][4];
  #pragma unroll
  for (int i = 0; i < 4; ++i)
    #pragma unroll
    for (int j = 0; j < 4; ++j)
      acc[i][j] = f32x4{0.f, 0.f, 0.f, 0.f};

  #pragma unroll
  for (int kk = 0; kk < 4; ++kk) {
    bf16x8 a[4], b[4];
    #pragma unroll
    for (int i = 0; i < 4; ++i) a[i] = *(const bf16x8*)(Abase + i * 4096 + kk * 64);
    #pragma unroll
    for (int j = 0; j < 4; ++j) b[j] = *(const bf16x8*)(Bbase + j * 4096 + kk * 64);
    #pragma unroll
    for (int i = 0; i < 4; ++i)
      #pragma unroll
      for (int j = 0; j < 4; ++j)
        acc[i][j] = __builtin_amdgcn_mfma_f32_16x16x32_bf16(a[i], b[j], acc[i][j], 0, 0, 0);
  }

  // epilogue: NT-store logits f32, track rowmin(ww-2L) and colmax(L)
  size_t growbase = (size_t)mt * 128 + wrow;
  int    gcolbase = nt * 128 + wcol;

  float wwj[4];
  #pragma unroll
  for (int j = 0; j < 4; ++j) wwj[j] = ww[gcolbase + j * 16 + l15];

  #pragma unroll
  for (int i = 0; i < 4; ++i) {
    #pragma unroll
    for (int r = 0; r < 4; ++r) {
      size_t grow = growbase + (size_t)(i * 16 + hi * 4 + r);
      float* lp = logits + grow * K_PROTO + gcolbase + l15;
      float vmin = 1e30f;
      #pragma unroll
      for (int j = 0; j < 4; ++j) {
        float lv = acc[i][j][r];
        __builtin_nontemporal_store(lv, lp + j * 16);
        vmin = fminf(vmin, wwj[j] - 2.0f * lv);
      }
      #pragma unroll
      for (int s2 = 1; s2 < 16; s2 <<= 1) vmin = fminf(vmin, __shfl_xor(vmin, s2, 64));
      if (l15 == 0) atomicMin(&rowmin_u[grow], map_f2u(vmin));
    }
  }

  #pragma unroll
  for (int j = 0; j < 4; ++j) {
    float vmax = -1e30f;
    #pragma unroll
    for (int i = 0; i < 4; ++i)
      #pragma unroll
      for (int r = 0; r < 4; ++r) vmax = fmaxf(vmax, acc[i][j][r]);
    vmax = fmaxf(vmax, __shfl_xor(vmax, 16, 64));
    vmax = fmaxf(vmax, __shfl_xor(vmax, 32, 64));
    if (hi == 0) atomicMax(&colmax_u[gcolbase + j * 16 + l15], map_f2u(vmax));
  }
}

// ---- K4: propagation = mean_n sqrt(max(1 + rowmin, 0)) ----
__global__ __launch_bounds__(1024) void prop_k(
    const unsigned int* __restrict__ rowmin_u, float* __restrict__ out) {
  __shared__ float sbuf[16];
  const uint4* p = (const uint4*)rowmin_u;  // 16384 uint4
  float s = 0.f;
  #pragma unroll
  for (int k = 0; k < 16; ++k) {
    uint4 u = p[threadIdx.x + 1024 * k];
    s += sqrtf(fmaxf(1.0f + unmap_u2f(u.x), 0.0f));
    s += sqrtf(fmaxf(1.0f + unmap_u2f(u.y), 0.0f));
    s += sqrtf(fmaxf(1.0f + unmap_u2f(u.z), 0.0f));
    s += sqrtf(fmaxf(1.0f + unmap_u2f(u.w), 0.0f));
  }
  #pragma unroll
  for (int off = 1; off < 64; off <<= 1) s += __shfl_xor(s, off, 64);
  int wid = threadIdx.x >> 6, lane = threadIdx.x & 63;
  if (lane == 0) sbuf[wid] = s;
  __syncthreads();
  if (threadIdx.x == 0) {
    float t = 0.f;
    #pragma unroll
    for (int w = 0; w < 16; ++w) t += sbuf[w];
    out[0] = t * (1.0f / N_CELLS);
  }
}

// ---- K5: emb_similarity = mean_k sqrt(max(1 + ww[k] - 2*colmax[k], 0)) ----
__global__ __launch_bounds__(1024) void emb_k(
    const unsigned int* __restrict__ colmax_u, const float* __restrict__ ww,
    float* __restrict__ out) {
  __shared__ float sbuf[16];
  float s = 0.f;
  for (int idx = threadIdx.x; idx < K_PROTO; idx += 1024)
    s += sqrtf(fmaxf(1.0f + ww[idx] - 2.0f * unmap_u2f(colmax_u[idx]), 0.0f));
  #pragma unroll
  for (int off = 1; off < 64; off <<= 1) s += __shfl_xor(s, off, 64);
  int wid = threadIdx.x >> 6, lane = threadIdx.x & 63;
  if (lane == 0) sbuf[wid] = s;
  __syncthreads();
  if (threadIdx.x == 0) {
    float t = 0.f;
    #pragma unroll
    for (int w = 0; w < 16; ++w) t += sbuf[w];
    out[0] = t * (1.0f / K_PROTO);
  }
}

extern "C" void kernel_launch(void* const* d_in, const int* in_sizes, int n_in,
                              void* d_out, int out_size, void* d_ws, size_t ws_size,
                              hipStream_t stream) {
  const float* x     = (const float*)d_in[0];
  const float* W     = (const float*)d_in[1];
  const float* recon = (const float*)d_in[2];
  const float* kl    = (const float*)d_in[3];
  const float* mmd   = (const float*)d_in[4];

  float* out    = (float*)d_out;
  float* z      = out;
  float* logits = out + (size_t)N_CELLS * D_DIM;
  float* scal   = logits + (size_t)N_CELLS * K_PROTO;  // [cvae, prop, emb]

  char* ws = (char*)d_ws;
  unsigned int* zb = (unsigned int*)ws;                     // 16 MiB packed bf16
  size_t off = (size_t)N_CELLS * D_DIM * 2;
  unsigned int* wb = (unsigned int*)(ws + off);             // 0.5 MiB
  off += (size_t)K_PROTO * D_DIM * 2;
  float* ww = (float*)(ws + off);                           // 8 KiB
  off += (size_t)K_PROTO * 4;
  unsigned int* rowmin_u = (unsigned int*)(ws + off);       // 256 KiB
  off += (size_t)N_CELLS * 4;
  unsigned int* colmax_u = (unsigned int*)(ws + off);       // 8 KiB

  normalize_k<<<N_CELLS / 4, 256, 0, stream>>>(x, z, zb, rowmin_u);
  wprep_k<<<K_PROTO / 4, 256, 0, stream>>>(W, wb, ww, colmax_u, recon, kl, mmd, scal);
  gemm_k<<<(N_CELLS / 128) * (K_PROTO / 128), 256, 0, stream>>>(
      (const unsigned short*)zb, (const unsigned short*)wb, ww, logits,
      rowmin_u, colmax_u);
  prop_k<<<1, 1024, 0, stream>>>(rowmin_u, scal + 1);
  emb_k<<<1, 1024, 0, stream>>>(colmax_u, ww, scal + 2);
}

// Round 4
// 220.883 us; speedup vs baseline: 1.2767x; 1.2696x over previous
//
#include <hip/hip_runtime.h>
#include <hip/hip_bf16.h>
#include <math.h>

#define N_CELLS 65536
#define D_DIM   128
#define K_PROTO 2048

typedef __attribute__((ext_vector_type(8))) short bf16x8;
typedef __attribute__((ext_vector_type(4))) float f32x4;

// ---- order-preserving float<->uint mapping for atomic min/max ----
__device__ __forceinline__ unsigned int map_f2u(float f) {
  unsigned int u = __float_as_uint(f);
  return (u & 0x80000000u) ? ~u : (u | 0x80000000u);
}
__device__ __forceinline__ float unmap_u2f(unsigned int u) {
  unsigned int b = (u & 0x80000000u) ? (u ^ 0x80000000u) : ~u;
  return __uint_as_float(b);
}

// RTN-even float -> bf16 bit pattern
__device__ __forceinline__ unsigned int f2bf(float f) {
  unsigned int u = __float_as_uint(f);
  return ((u + 0x7FFFu + ((u >> 16) & 1u)) >> 16) & 0xFFFFu;
}

// ---- K1: row-normalize x -> z (NT float4 out) + zb (packed bf16) + rowmin init ----
__global__ __launch_bounds__(256) void normalize_k(
    const float* __restrict__ x, float* __restrict__ z,
    unsigned int* __restrict__ zb, unsigned int* __restrict__ rowmin_u) {
  int tid = threadIdx.x;
  int sub = tid & 31;                       // lane within half-wave = col group
  int row = blockIdx.x * 8 + (tid >> 5);    // one row per 32 lanes
  const f32x4* xr = (const f32x4*)(x + (size_t)row * D_DIM);
  f32x4 v = xr[sub];
  float s = v.x * v.x + v.y * v.y + v.z * v.z + v.w * v.w;
  #pragma unroll
  for (int off = 1; off < 32; off <<= 1) s += __shfl_xor(s, off, 64);
  float inv = 1.0f / fmaxf(sqrtf(s), 1e-12f);
  f32x4 zv = v * inv;
  __builtin_nontemporal_store(zv, (f32x4*)(z + (size_t)row * D_DIM) + sub);
  unsigned int lo = (f2bf(zv.y) << 16) | f2bf(zv.x);
  unsigned int h2 = (f2bf(zv.w) << 16) | f2bf(zv.z);
  unsigned long long pk = ((unsigned long long)h2 << 32) | lo;
  *((unsigned long long*)(zb + (size_t)row * (D_DIM / 2)) + sub) = pk;
  if (sub == 0) rowmin_u[row] = 0xFFFFFFFFu;  // min identity (mapped order)
}

// ---- K2: W -> bf16 + ww norms + colmax init; block 0 writes cvae ----
__global__ __launch_bounds__(256) void wprep_k(
    const float* __restrict__ W, unsigned int* __restrict__ wb,
    float* __restrict__ ww, unsigned int* __restrict__ colmax_u,
    const float* __restrict__ recon, const float* __restrict__ kl,
    const float* __restrict__ mmd, float* __restrict__ scal) {
  if (blockIdx.x == 0 && threadIdx.x == 0) {
    scal[0] = recon[0] + 0.5f * kl[0] + mmd[0];  // cvae_loss
  }
  int tid = threadIdx.x;
  int sub = tid & 31;
  int row = blockIdx.x * 8 + (tid >> 5);
  const f32x4* wr = (const f32x4*)(W + (size_t)row * D_DIM);
  f32x4 v = wr[sub];
  float s = v.x * v.x + v.y * v.y + v.z * v.z + v.w * v.w;
  #pragma unroll
  for (int off = 1; off < 32; off <<= 1) s += __shfl_xor(s, off, 64);
  if (sub == 0) {
    ww[row] = s;
    colmax_u[row] = 0u;  // max identity (mapped order)
  }
  unsigned int lo = (f2bf(v.y) << 16) | f2bf(v.x);
  unsigned int h2 = (f2bf(v.w) << 16) | f2bf(v.z);
  unsigned long long pk = ((unsigned long long)h2 << 32) | lo;
  *((unsigned long long*)(wb + (size_t)row * (D_DIM / 2)) + sub) = pk;
}

// ---- K3: LDS-free GEMM, swapped operands -> dwordx4 logits stores ----
__global__ __launch_bounds__(256) void gemm_k(
    const unsigned short* __restrict__ zb, const unsigned short* __restrict__ wb,
    const float* __restrict__ ww, float* __restrict__ logits,
    unsigned int* __restrict__ rowmin_u, unsigned int* __restrict__ colmax_u) {
  // XCD-chunked bijective swizzle: 8192 blocks = 8 XCDs x 1024
  int bid = blockIdx.x;
  int swz = (bid & 7) * 1024 + (bid >> 3);
  int nt  = swz & 15;   // 16 col tiles (protos)
  int mt  = swz >> 4;   // 512 row tiles (cells)

  int tid  = threadIdx.x;
  int lane = tid & 63;
  int wid  = tid >> 6;
  int wrow = (wid >> 1) * 64;   // cell offset within tile
  int wcol = (wid & 1) * 64;    // proto offset within tile
  int l15  = lane & 15;
  int hi   = lane >> 4;

  // fragment base addresses: row-major bf16, 256 B per row
  const char* Abase = (const char*)zb + ((size_t)(mt * 128 + wrow + l15) * 256 + hi * 16);
  const char* Bbase = (const char*)wb + ((size_t)(nt * 128 + wcol + l15) * 256 + hi * 16);

  f32x4 acc[4][4];
  #pragma unroll
  for (int i = 0; i < 4; ++i)
    #pragma unroll
    for (int j = 0; j < 4; ++j)
      acc[i][j] = f32x4{0.f, 0.f, 0.f, 0.f};

  #pragma unroll
  for (int kk = 0; kk < 4; ++kk) {
    bf16x8 a[4], b[4];
    #pragma unroll
    for (int i = 0; i < 4; ++i) a[i] = *(const bf16x8*)(Abase + i * 4096 + kk * 64);
    #pragma unroll
    for (int j = 0; j < 4; ++j) b[j] = *(const bf16x8*)(Bbase + j * 4096 + kk * 64);
    // SWAPPED: M-operand = protos, N-operand = cells  =>  C/D reg axis = protos
    #pragma unroll
    for (int i = 0; i < 4; ++i)
      #pragma unroll
      for (int j = 0; j < 4; ++j)
        acc[i][j] = __builtin_amdgcn_mfma_f32_16x16x32_bf16(b[j], a[i], acc[i][j], 0, 0, 0);
  }

  // lane (hi,l15), acc[i][j][r]: cell = growbase + i*16 + l15
  //                              proto = gcolbase + j*16 + hi*4 + r
  size_t growbase = (size_t)mt * 128 + wrow;
  int    gcolbase = nt * 128 + wcol;

  f32x4 wwj[4];
  #pragma unroll
  for (int j = 0; j < 4; ++j)
    wwj[j] = *(const f32x4*)(ww + gcolbase + j * 16 + hi * 4);

  // store logits (dwordx4) + rowmin(ww - 2L) tracking
  #pragma unroll
  for (int i = 0; i < 4; ++i) {
    size_t row = growbase + (size_t)(i * 16 + l15);
    float* lp = logits + row * K_PROTO + gcolbase + hi * 4;
    float vmin = 1e30f;
    #pragma unroll
    for (int j = 0; j < 4; ++j) {
      f32x4 c = acc[i][j];
      __builtin_nontemporal_store(c, (f32x4*)(lp + j * 16));
      #pragma unroll
      for (int r = 0; r < 4; ++r) vmin = fminf(vmin, wwj[j][r] - 2.0f * c[r]);
    }
    vmin = fminf(vmin, __shfl_xor(vmin, 16, 64));
    vmin = fminf(vmin, __shfl_xor(vmin, 32, 64));
    if (hi == 0) atomicMin(&rowmin_u[row], map_f2u(vmin));
  }

  // colmax(L) per proto: reduce over cells (i regs + l15 lanes)
  #pragma unroll
  for (int j = 0; j < 4; ++j) {
    f32x4 m = acc[0][j];
    #pragma unroll
    for (int i = 1; i < 4; ++i)
      #pragma unroll
      for (int r = 0; r < 4; ++r) m[r] = fmaxf(m[r], acc[i][j][r]);
    #pragma unroll
    for (int s2 = 1; s2 < 16; s2 <<= 1)
      #pragma unroll
      for (int r = 0; r < 4; ++r) m[r] = fmaxf(m[r], __shfl_xor(m[r], s2, 64));
    if (l15 == 0) {
      #pragma unroll
      for (int r = 0; r < 4; ++r)
        atomicMax(&colmax_u[gcolbase + j * 16 + hi * 4 + r], map_f2u(m[r]));
    }
  }
}

// ---- K4: propagation = mean_n sqrt(max(1 + rowmin, 0)) ----
__global__ __launch_bounds__(1024) void prop_k(
    const unsigned int* __restrict__ rowmin_u, float* __restrict__ out) {
  __shared__ float sbuf[16];
  const uint4* p = (const uint4*)rowmin_u;  // 16384 uint4
  float s = 0.f;
  #pragma unroll
  for (int k = 0; k < 16; ++k) {
    uint4 u = p[threadIdx.x + 1024 * k];
    s += sqrtf(fmaxf(1.0f + unmap_u2f(u.x), 0.0f));
    s += sqrtf(fmaxf(1.0f + unmap_u2f(u.y), 0.0f));
    s += sqrtf(fmaxf(1.0f + unmap_u2f(u.z), 0.0f));
    s += sqrtf(fmaxf(1.0f + unmap_u2f(u.w), 0.0f));
  }
  #pragma unroll
  for (int off = 1; off < 64; off <<= 1) s += __shfl_xor(s, off, 64);
  int wid = threadIdx.x >> 6, lane = threadIdx.x & 63;
  if (lane == 0) sbuf[wid] = s;
  __syncthreads();
  if (threadIdx.x == 0) {
    float t = 0.f;
    #pragma unroll
    for (int w = 0; w < 16; ++w) t += sbuf[w];
    out[0] = t * (1.0f / N_CELLS);
  }
}

// ---- K5: emb_similarity = mean_k sqrt(max(1 + ww[k] - 2*colmax[k], 0)) ----
__global__ __launch_bounds__(1024) void emb_k(
    const unsigned int* __restrict__ colmax_u, const float* __restrict__ ww,
    float* __restrict__ out) {
  __shared__ float sbuf[16];
  float s = 0.f;
  for (int idx = threadIdx.x; idx < K_PROTO; idx += 1024)
    s += sqrtf(fmaxf(1.0f + ww[idx] - 2.0f * unmap_u2f(colmax_u[idx]), 0.0f));
  #pragma unroll
  for (int off = 1; off < 64; off <<= 1) s += __shfl_xor(s, off, 64);
  int wid = threadIdx.x >> 6, lane = threadIdx.x & 63;
  if (lane == 0) sbuf[wid] = s;
  __syncthreads();
  if (threadIdx.x == 0) {
    float t = 0.f;
    #pragma unroll
    for (int w = 0; w < 16; ++w) t += sbuf[w];
    out[0] = t * (1.0f / K_PROTO);
  }
}

extern "C" void kernel_launch(void* const* d_in, const int* in_sizes, int n_in,
                              void* d_out, int out_size, void* d_ws, size_t ws_size,
                              hipStream_t stream) {
  const float* x     = (const float*)d_in[0];
  const float* W     = (const float*)d_in[1];
  const float* recon = (const float*)d_in[2];
  const float* kl    = (const float*)d_in[3];
  const float* mmd   = (const float*)d_in[4];

  float* out    = (float*)d_out;
  float* z      = out;
  float* logits = out + (size_t)N_CELLS * D_DIM;
  float* scal   = logits + (size_t)N_CELLS * K_PROTO;  // [cvae, prop, emb]

  char* ws = (char*)d_ws;
  unsigned int* zb = (unsigned int*)ws;                     // 16 MiB packed bf16
  size_t off = (size_t)N_CELLS * D_DIM * 2;
  unsigned int* wb = (unsigned int*)(ws + off);             // 0.5 MiB
  off += (size_t)K_PROTO * D_DIM * 2;
  float* ww = (float*)(ws + off);                           // 8 KiB
  off += (size_t)K_PROTO * 4;
  unsigned int* rowmin_u = (unsigned int*)(ws + off);       // 256 KiB
  off += (size_t)N_CELLS * 4;
  unsigned int* colmax_u = (unsigned int*)(ws + off);       // 8 KiB

  normalize_k<<<N_CELLS / 8, 256, 0, stream>>>(x, z, zb, rowmin_u);
  wprep_k<<<K_PROTO / 8, 256, 0, stream>>>(W, wb, ww, colmax_u, recon, kl, mmd, scal);
  gemm_k<<<(N_CELLS / 128) * (K_PROTO / 128), 256, 0, stream>>>(
      (const unsigned short*)zb, (const unsigned short*)wb, ww, logits,
      rowmin_u, colmax_u);
  prop_k<<<1, 1024, 0, stream>>>(rowmin_u, scal + 1);
  emb_k<<<1, 1024, 0, stream>>>(colmax_u, ww, scal + 2);
}